// Round 1
// baseline (740.740 us; speedup 1.0000x reference)
//
#include <hip/hip_runtime.h>
#include <cstdint>
#include <cstddef>

#define DEVFN static __device__ __forceinline__

typedef __attribute__((ext_vector_type(8))) short shortx8;   // 8 bf16 (4 VGPRs)
typedef __attribute__((ext_vector_type(4))) float floatx4;   // 4 f32

DEVFN float bf2f(unsigned short u) {
  union { unsigned int i; float f; } v; v.i = ((unsigned int)u) << 16; return v.f;
}
DEVFN unsigned short f2bf(float f) {
  union { float f; unsigned int i; } v; v.f = f;
  unsigned int r = v.i + 0x7FFFu + ((v.i >> 16) & 1u);
  return (unsigned short)(r >> 16);
}

DEVFN void gload_lds16(const void* g, void* l) {
  __builtin_amdgcn_global_load_lds(
      (const __attribute__((address_space(1))) void*)(uintptr_t)g,
      (__attribute__((address_space(3))) void*)(uint32_t)(uintptr_t)l,
      16, 0, 0);
}

// ---------------- CSR build ----------------

__global__ void count_edges(const int* __restrict__ dc, const int* __restrict__ dw,
                            const int* __restrict__ dr,
                            int* cntC, int* cntW, int* cntR, int E_) {
  int i = blockIdx.x * blockDim.x + threadIdx.x;
  const int stride = gridDim.x * blockDim.x;
  for (; i < 3 * E_; i += stride) {
    if (i < E_)            atomicAdd(&cntC[dc[i]], 1);
    else if (i < 2 * E_)   atomicAdd(&cntW[dw[i - E_]], 1);
    else                   atomicAdd(&cntR[dr[i - 2 * E_]], 1);
  }
}

// 3 blocks; block b scans its array: counts -> rowptr (exclusive), cursor(=counts buf), invdeg
__global__ void scan3(int* cA, int* rA, float* vA, int nA,
                      int* cB, int* rB, float* vB, int nB,
                      int* cC, int* rC, float* vC, int nC) {
  int* cnt; int* rp; float* inv; int n;
  if (blockIdx.x == 0)      { cnt = cA; rp = rA; inv = vA; n = nA; }
  else if (blockIdx.x == 1) { cnt = cB; rp = rB; inv = vB; n = nB; }
  else                      { cnt = cC; rp = rC; inv = vC; n = nC; }
  __shared__ int sd[1024];
  const int t = threadIdx.x;
  int run = 0;
  for (int base = 0; base < n; base += 1024) {
    const int i = base + t;
    const int v = (i < n) ? cnt[i] : 0;
    sd[t] = v; __syncthreads();
    for (int off = 1; off < 1024; off <<= 1) {
      int y = (t >= off) ? sd[t - off] : 0;
      __syncthreads();
      sd[t] += y;
      __syncthreads();
    }
    const int incl = sd[t];
    const int total = sd[1023];
    const int excl = run + incl - v;
    if (i < n) {
      rp[i] = excl;
      cnt[i] = excl;  // cursor for fill pass
      inv[i] = 1.0f / (float)(v > 1 ? v : 1);
    }
    run += total;
    __syncthreads();
  }
  if (t == 0) rp[n] = run;
}

__global__ void fill_edges(const int* __restrict__ sc, const int* __restrict__ dc,
                           const int* __restrict__ sw, const int* __restrict__ dw,
                           const int* __restrict__ sr, const int* __restrict__ dr,
                           int* curC, int* curW, int* curR,
                           int* eC, int* eW, int* eR, int E_) {
  int i = blockIdx.x * blockDim.x + threadIdx.x;
  const int stride = gridDim.x * blockDim.x;
  for (; i < 3 * E_; i += stride) {
    if (i < E_)          { int p = atomicAdd(&curC[dc[i]], 1); eC[p] = sc[i]; }
    else if (i < 2 * E_) { int j = i - E_;     int p = atomicAdd(&curW[dw[j]], 1); eW[p] = sw[j]; }
    else                 { int j = i - 2 * E_; int p = atomicAdd(&curR[dr[j]], 1); eR[p] = sr[j]; }
  }
}

// ---------------- f32 -> bf16 convert ----------------

__global__ void cvt_bf16(const float4* __restrict__ a, unsigned short* __restrict__ oa, long na4,
                         const float4* __restrict__ b, unsigned short* __restrict__ ob, long nb4) {
  long i = (long)blockIdx.x * blockDim.x + threadIdx.x;
  const long tot = na4 + nb4;
  const long stride = (long)gridDim.x * blockDim.x;
  for (; i < tot; i += stride) {
    const float4* src; unsigned short* dst; long j;
    if (i < na4) { src = a; dst = oa; j = i; } else { src = b; dst = ob; j = i - na4; }
    float4 v = src[j];
    ushort4 o;
    o.x = f2bf(v.x); o.y = f2bf(v.y); o.z = f2bf(v.z); o.w = f2bf(v.w);
    *(ushort4*)(dst + j * 4) = o;
  }
}

// ---------------- weight prep: build W^T [N=256][K] bf16 + combined biases ----------------

__global__ void prep_w(const float* Wl1c, const float* bl1c, const float* Wr1c,
                       const float* Wl1w, const float* bl1w, const float* Wr1w,
                       const float* Wl1r, const float* bl1r, const float* Wr1r,
                       const float* Wl2c, const float* bl2c, const float* Wr2c,
                       const float* Wl2w, const float* bl2w, const float* Wr2w,
                       const float* Wl2r, const float* bl2r, const float* Wr2r,
                       unsigned short* WT, float* bias) {
  const int mat = blockIdx.x >> 8;
  const int nn = blockIdx.x & 255;
  const int t = threadIdx.x;
  if (mat == 0) {  // P1: K=640 = [Wl1c(256); Wl1w(128); Wr1c+Wr1w(256)]
    unsigned short* out = WT + (size_t)nn * 640;
    for (int k = t; k < 640; k += 256) {
      float v;
      if (k < 256)      v = Wl1c[k * 256 + nn];
      else if (k < 384) v = Wl1w[(k - 256) * 256 + nn];
      else              v = Wr1c[(k - 384) * 256 + nn] + Wr1w[(k - 384) * 256 + nn];
      out[k] = f2bf(v);
    }
    if (t == 0) bias[nn] = bl1c[nn] + bl1w[nn];
  } else if (mat == 1) {  // A1: K=384 = [Wl1r(256); Wr1r(128)]
    unsigned short* out = WT + (size_t)256 * 640 + (size_t)nn * 384;
    for (int k = t; k < 384; k += 256) {
      float v = (k < 256) ? Wl1r[k * 256 + nn] : Wr1r[(k - 256) * 256 + nn];
      out[k] = f2bf(v);
    }
    if (t == 0) bias[256 + nn] = bl1r[nn];
  } else if (mat == 2) {  // P2: K=768 = [Wl2c(256); Wl2w(256); Wr2c+Wr2w(256)]
    unsigned short* out = WT + (size_t)256 * (640 + 384) + (size_t)nn * 768;
    for (int k = t; k < 768; k += 256) {
      float v;
      if (k < 256)      v = Wl2c[k * 256 + nn];
      else if (k < 512) v = Wl2w[(k - 256) * 256 + nn];
      else              v = Wr2c[(k - 512) * 256 + nn] + Wr2w[(k - 512) * 256 + nn];
      out[k] = f2bf(v);
    }
    if (t == 0) bias[512 + nn] = bl2c[nn] + bl2w[nn];
  } else {  // A2: K=512 = [Wl2r(256); Wr2r(256)]
    unsigned short* out = WT + (size_t)256 * (640 + 384 + 768) + (size_t)nn * 512;
    for (int k = t; k < 512; k += 256) {
      float v = (k < 256) ? Wl2r[k * 256 + nn] : Wr2r[(k - 256) * 256 + nn];
      out[k] = f2bf(v);
    }
    if (t == 0) bias[768 + nn] = bl2r[nn];
  }
}

// ---------------- aggregation: one wave per dst node, mean of bf16 source rows ----------------

template <int D>
__global__ __launch_bounds__(256)
void agg_mean(const unsigned short* __restrict__ feat, const int* __restrict__ rp,
              const int* __restrict__ es, const float* __restrict__ inv,
              unsigned short* __restrict__ out, int n) {
  const int node = blockIdx.x * 4 + (threadIdx.x >> 6);
  const int lane = threadIdx.x & 63;
  if (node >= n) return;
  const int e0 = rp[node], e1 = rp[node + 1];
  const float sc = inv[node];
  if constexpr (D == 256) {
    const int c0 = lane * 4;
    float a0 = 0, a1 = 0, a2 = 0, a3 = 0;
    int e = e0;
    for (; e + 1 < e1; e += 2) {
      int s0 = es[e], s1 = es[e + 1];
      ushort4 v0 = *(const ushort4*)(feat + (size_t)s0 * 256 + c0);
      ushort4 v1 = *(const ushort4*)(feat + (size_t)s1 * 256 + c0);
      a0 += bf2f(v0.x) + bf2f(v1.x);
      a1 += bf2f(v0.y) + bf2f(v1.y);
      a2 += bf2f(v0.z) + bf2f(v1.z);
      a3 += bf2f(v0.w) + bf2f(v1.w);
    }
    if (e < e1) {
      int s0 = es[e];
      ushort4 v0 = *(const ushort4*)(feat + (size_t)s0 * 256 + c0);
      a0 += bf2f(v0.x); a1 += bf2f(v0.y); a2 += bf2f(v0.z); a3 += bf2f(v0.w);
    }
    ushort4 o;
    o.x = f2bf(a0 * sc); o.y = f2bf(a1 * sc); o.z = f2bf(a2 * sc); o.w = f2bf(a3 * sc);
    *(ushort4*)(out + (size_t)node * 256 + c0) = o;
  } else {
    const int c0 = lane * 2;
    float a0 = 0, a1 = 0;
    int e = e0;
    for (; e + 1 < e1; e += 2) {
      int s0 = es[e], s1 = es[e + 1];
      ushort2 v0 = *(const ushort2*)(feat + (size_t)s0 * 128 + c0);
      ushort2 v1 = *(const ushort2*)(feat + (size_t)s1 * 128 + c0);
      a0 += bf2f(v0.x) + bf2f(v1.x);
      a1 += bf2f(v0.y) + bf2f(v1.y);
    }
    if (e < e1) {
      int s0 = es[e];
      ushort2 v0 = *(const ushort2*)(feat + (size_t)s0 * 128 + c0);
      a0 += bf2f(v0.x); a1 += bf2f(v0.y);
    }
    ushort2 o; o.x = f2bf(a0 * sc); o.y = f2bf(a1 * sc);
    *(ushort2*)(out + (size_t)node * 128 + c0) = o;
  }
}

// ---------------- segmented-A bf16 MFMA GEMM: C[M x 256] = [segA] @ W^T + bias ----------------

struct Segs {
  const unsigned short *p0, *p1, *p2;
  int ld0, ld1, ld2;
  int ke0, ke1;  // segment end k-offsets (elements); seg2 ends at KTOT
};

template <int KTOT, bool RELU, bool OBF16>
__global__ __launch_bounds__(256, 2)
void gemm_sage(Segs sg, const unsigned short* __restrict__ Wt,
               const float* __restrict__ bias, void* __restrict__ outp, int M) {
  __shared__ alignas(16) unsigned short lsA[128 * 64];
  __shared__ alignas(16) unsigned short lsB[128 * 64];

  const int tid = threadIdx.x;
  const int lane = tid & 63;
  const int wave = tid >> 6;
  const int wr = wave >> 1, wc = wave & 1;
  const int mt = blockIdx.x >> 1, nt = blockIdx.x & 1;

  const floatx4 fzero = {0.f, 0.f, 0.f, 0.f};
  floatx4 acc[4][4];
#pragma unroll
  for (int m = 0; m < 4; ++m)
#pragma unroll
    for (int n = 0; n < 4; ++n) acc[m][n] = fzero;

  const int srow = tid >> 3;        // 0..31: tile row chunk per staging stmt
  const int scol = (tid & 7) * 8;   // element offset within 64-wide k-tile (16B)
  const int arow = wr * 64 + (lane & 15);
  const int brow = wc * 64 + (lane & 15);
  const int kq = (lane >> 4) * 8;

  constexpr int KT = KTOT / 64;
#pragma unroll 1
  for (int kt = 0; kt < KT; ++kt) {
    const int k0 = kt * 64;
    const unsigned short* sp; int sld, skb;
    if (k0 < sg.ke0)      { sp = sg.p0; sld = sg.ld0; skb = 0; }
    else if (k0 < sg.ke1) { sp = sg.p1; sld = sg.ld1; skb = sg.ke0; }
    else                  { sp = sg.p2; sld = sg.ld2; skb = sg.ke1; }

#pragma unroll
    for (int s = 0; s < 4; ++s) {
      int r = s * 32 + srow;
      int g = mt * 128 + r; g = g < M ? g : M - 1;
      gload_lds16(sp + (size_t)g * sld + (k0 - skb) + scol, lsA + r * 64 + scol);
    }
#pragma unroll
    for (int s = 0; s < 4; ++s) {
      int r = s * 32 + srow;
      gload_lds16(Wt + (size_t)(nt * 128 + r) * KTOT + k0 + scol, lsB + r * 64 + scol);
    }
    __syncthreads();  // drain global_load_lds (compiler emits vmcnt(0)) + barrier

    shortx8 af[2][4], bq[2][4];
#pragma unroll
    for (int kk = 0; kk < 2; ++kk)
#pragma unroll
      for (int i = 0; i < 4; ++i) {
        af[kk][i] = *(const shortx8*)(lsA + (arow + i * 16) * 64 + kk * 32 + kq);
        bq[kk][i] = *(const shortx8*)(lsB + (brow + i * 16) * 64 + kk * 32 + kq);
      }
#pragma unroll
    for (int m = 0; m < 4; ++m)
#pragma unroll
      for (int n = 0; n < 4; ++n) {
        acc[m][n] = __builtin_amdgcn_mfma_f32_16x16x32_bf16(af[0][m], bq[0][n], acc[m][n], 0, 0, 0);
        acc[m][n] = __builtin_amdgcn_mfma_f32_16x16x32_bf16(af[1][m], bq[1][n], acc[m][n], 0, 0, 0);
      }
    __syncthreads();  // protect LDS before next stage
  }

  const int lr = (lane >> 4) * 4;
  const int lc = lane & 15;
  const int rb = mt * 128 + wr * 64;
  const int cb = nt * 128 + wc * 64;
#pragma unroll
  for (int m = 0; m < 4; ++m) {
#pragma unroll
    for (int j = 0; j < 4; ++j) {
      const int row = rb + m * 16 + lr + j;
      if (row < M) {
#pragma unroll
        for (int n = 0; n < 4; ++n) {
          const int col = cb + n * 16 + lc;
          float v = acc[m][n][j] + bias[col];
          if (RELU) v = v > 0.f ? v : 0.f;
          if (OBF16) ((unsigned short*)outp)[(size_t)row * 256 + col] = f2bf(v);
          else       ((float*)outp)[(size_t)row * 256 + col] = v;
        }
      }
    }
  }
}

// ---------------- host ----------------

extern "C" void kernel_launch(void* const* d_in, const int* in_sizes, int n_in,
                              void* d_out, int out_size, void* d_ws, size_t ws_size,
                              hipStream_t stream) {
  const float* x_paper = (const float*)d_in[0];
  const float* x_author = (const float*)d_in[1];
  const int* cites_src = (const int*)d_in[2];
  const int* cites_dst = (const int*)d_in[3];
  const int* writes_src = (const int*)d_in[4];
  const int* writes_dst = (const int*)d_in[5];
  const int* rev_src = (const int*)d_in[6];
  const int* rev_dst = (const int*)d_in[7];
  const float* Wl1c = (const float*)d_in[8];  const float* bl1c = (const float*)d_in[9];  const float* Wr1c = (const float*)d_in[10];
  const float* Wl1w = (const float*)d_in[11]; const float* bl1w = (const float*)d_in[12]; const float* Wr1w = (const float*)d_in[13];
  const float* Wl1r = (const float*)d_in[14]; const float* bl1r = (const float*)d_in[15]; const float* Wr1r = (const float*)d_in[16];
  const float* Wl2c = (const float*)d_in[17]; const float* bl2c = (const float*)d_in[18]; const float* Wr2c = (const float*)d_in[19];
  const float* Wl2w = (const float*)d_in[20]; const float* bl2w = (const float*)d_in[21]; const float* Wr2w = (const float*)d_in[22];
  const float* Wl2r = (const float*)d_in[23]; const float* bl2r = (const float*)d_in[24]; const float* Wr2r = (const float*)d_in[25];

  const int NP = in_sizes[0] / 256;  // 50000
  const int NA = in_sizes[1] / 128;  // 25000
  const int E = in_sizes[2];         // 400000

  char* w = (char*)d_ws;
  auto alloc = [&](size_t bytes) -> char* {
    char* p = w;
    w += (bytes + 255) & ~(size_t)255;
    return p;
  };

  unsigned short* xpb = (unsigned short*)alloc((size_t)NP * 256 * 2);
  unsigned short* xab = (unsigned short*)alloc((size_t)NA * 128 * 2);
  unsigned short* mA  = (unsigned short*)alloc((size_t)NP * 256 * 2);
  unsigned short* mB  = (unsigned short*)alloc((size_t)NP * 256 * 2);
  unsigned short* mC  = (unsigned short*)alloc((size_t)NA * 256 * 2);
  unsigned short* p1b = (unsigned short*)alloc((size_t)NP * 256 * 2);
  unsigned short* a1b = (unsigned short*)alloc((size_t)NA * 256 * 2);
  unsigned short* WT  = (unsigned short*)alloc((size_t)2304 * 256 * 2);
  float* bias = (float*)alloc(4 * 256 * 4);
  int* curC = (int*)alloc((size_t)NP * 4);
  int* curW = (int*)alloc((size_t)NP * 4);
  int* curR = (int*)alloc((size_t)NA * 4);
  int* rpC = (int*)alloc((size_t)(NP + 1) * 4);
  int* rpW = (int*)alloc((size_t)(NP + 1) * 4);
  int* rpR = (int*)alloc((size_t)(NA + 1) * 4);
  float* invC = (float*)alloc((size_t)NP * 4);
  float* invW = (float*)alloc((size_t)NP * 4);
  float* invR = (float*)alloc((size_t)NA * 4);
  int* esC = (int*)alloc((size_t)E * 4);
  int* esW = (int*)alloc((size_t)E * 4);
  int* esR = (int*)alloc((size_t)E * 4);

  // zero edge-count arrays
  hipMemsetAsync(curC, 0, (size_t)NP * 4, stream);
  hipMemsetAsync(curW, 0, (size_t)NP * 4, stream);
  hipMemsetAsync(curR, 0, (size_t)NA * 4, stream);

  // weights (independent) + feature converts
  prep_w<<<1024, 256, 0, stream>>>(Wl1c, bl1c, Wr1c, Wl1w, bl1w, Wr1w, Wl1r, bl1r, Wr1r,
                                   Wl2c, bl2c, Wr2c, Wl2w, bl2w, Wr2w, Wl2r, bl2r, Wr2r,
                                   WT, bias);
  cvt_bf16<<<2048, 256, 0, stream>>>((const float4*)x_paper, xpb, (long)NP * 256 / 4,
                                     (const float4*)x_author, xab, (long)NA * 128 / 4);

  // CSR build (shared by both layers)
  count_edges<<<2048, 256, 0, stream>>>(cites_dst, writes_dst, rev_dst, curC, curW, curR, E);
  scan3<<<3, 1024, 0, stream>>>(curC, rpC, invC, NP, curW, rpW, invW, NP, curR, rpR, invR, NA);
  fill_edges<<<2048, 256, 0, stream>>>(cites_src, cites_dst, writes_src, writes_dst, rev_src, rev_dst,
                                       curC, curW, curR, esC, esW, esR, E);

  // layer-1 aggregation
  agg_mean<256><<<(NP + 3) / 4, 256, 0, stream>>>(xpb, rpC, esC, invC, mA, NP);
  agg_mean<128><<<(NP + 3) / 4, 256, 0, stream>>>(xab, rpW, esW, invW, mB, NP);
  agg_mean<256><<<(NA + 3) / 4, 256, 0, stream>>>(xpb, rpR, esR, invR, mC, NA);

  // layer-1 GEMMs (relu, bf16 out)
  {
    Segs s; s.p0 = mA; s.ld0 = 256; s.ke0 = 256;
    s.p1 = mB; s.ld1 = 128; s.ke1 = 384;
    s.p2 = xpb; s.ld2 = 256;
    gemm_sage<640, true, true><<<((NP + 127) / 128) * 2, 256, 0, stream>>>(s, WT, bias, p1b, NP);
  }
  {
    Segs s; s.p0 = mC; s.ld0 = 256; s.ke0 = 256;
    s.p1 = xab; s.ld1 = 128; s.ke1 = 384;
    s.p2 = xab; s.ld2 = 128;
    gemm_sage<384, true, true><<<((NA + 127) / 128) * 2, 256, 0, stream>>>(
        s, WT + (size_t)256 * 640, bias + 256, a1b, NA);
  }

  // layer-2 aggregation (reuse CSR)
  agg_mean<256><<<(NP + 3) / 4, 256, 0, stream>>>(p1b, rpC, esC, invC, mA, NP);
  agg_mean<256><<<(NP + 3) / 4, 256, 0, stream>>>(a1b, rpW, esW, invW, mB, NP);
  agg_mean<256><<<(NA + 3) / 4, 256, 0, stream>>>(p1b, rpR, esR, invR, mC, NA);

  // layer-2 GEMMs (no relu, f32 out -> d_out)
  {
    Segs s; s.p0 = mA; s.ld0 = 256; s.ke0 = 256;
    s.p1 = mB; s.ld1 = 256; s.ke1 = 512;
    s.p2 = p1b; s.ld2 = 256;
    gemm_sage<768, false, false><<<((NP + 127) / 128) * 2, 256, 0, stream>>>(
        s, WT + (size_t)256 * (640 + 384), bias + 512, d_out, NP);
  }
  {
    Segs s; s.p0 = mC; s.ld0 = 256; s.ke0 = 256;
    s.p1 = a1b; s.ld1 = 256; s.ke1 = 512;
    s.p2 = a1b; s.ld2 = 256;
    gemm_sage<512, false, false><<<((NA + 127) / 128) * 2, 256, 0, stream>>>(
        s, WT + (size_t)256 * (640 + 384 + 768), bias + 768,
        (float*)d_out + (size_t)NP * 256, NA);
  }
}

// Round 2
// 603.393 us; speedup vs baseline: 1.2276x; 1.2276x over previous
//
#include <hip/hip_runtime.h>
#include <cstdint>
#include <cstddef>

#define DEVFN static __device__ __forceinline__

typedef __attribute__((ext_vector_type(8))) short shortx8;   // 8 bf16 (4 VGPRs)
typedef __attribute__((ext_vector_type(4))) float floatx4;   // 4 f32

DEVFN float bf2f(unsigned short u) {
  union { unsigned int i; float f; } v; v.i = ((unsigned int)u) << 16; return v.f;
}
DEVFN unsigned short f2bf(float f) {
  union { float f; unsigned int i; } v; v.f = f;
  unsigned int r = v.i + 0x7FFFu + ((v.i >> 16) & 1u);
  return (unsigned short)(r >> 16);
}

DEVFN void gload_lds16(const void* g, void* l) {
  __builtin_amdgcn_global_load_lds(
      (const __attribute__((address_space(1))) void*)(uintptr_t)g,
      (__attribute__((address_space(3))) void*)(uint32_t)(uintptr_t)l,
      16, 0, 0);
}

// ---------------- CSR build ----------------

__global__ void count_edges(const int* __restrict__ dc, const int* __restrict__ dw,
                            const int* __restrict__ dr,
                            int* cntC, int* cntW, int* cntR, int E_) {
  int i = blockIdx.x * blockDim.x + threadIdx.x;
  const int stride = gridDim.x * blockDim.x;
  for (; i < 3 * E_; i += stride) {
    if (i < E_)            atomicAdd(&cntC[dc[i]], 1);
    else if (i < 2 * E_)   atomicAdd(&cntW[dw[i - E_]], 1);
    else                   atomicAdd(&cntR[dr[i - 2 * E_]], 1);
  }
}

// hierarchical exclusive scan over three arrays; 1024 elems per block.
// pass 1: per-block sums
__global__ __launch_bounds__(256)
void scan_pass1(const int* __restrict__ cC, int nC,
                const int* __restrict__ cW, int nW,
                const int* __restrict__ cR, int nR,
                int* __restrict__ bs, int nbC, int nbW) {
  const int b = blockIdx.x;
  const int* cnt; int n, lb, bsoff;
  if (b < nbC)            { cnt = cC; n = nC; lb = b;             bsoff = 0; }
  else if (b < nbC + nbW) { cnt = cW; n = nW; lb = b - nbC;       bsoff = nbC; }
  else                    { cnt = cR; n = nR; lb = b - nbC - nbW; bsoff = nbC + nbW; }
  const int t = threadIdx.x, lane = t & 63, wid = t >> 6;
  const int base = lb * 1024 + t * 4;
  int c0 = 0, c1 = 0, c2 = 0, c3 = 0;
  if (base + 3 < n) { int4 q = *(const int4*)(cnt + base); c0 = q.x; c1 = q.y; c2 = q.z; c3 = q.w; }
  else {
    if (base < n)     c0 = cnt[base];
    if (base + 1 < n) c1 = cnt[base + 1];
    if (base + 2 < n) c2 = cnt[base + 2];
  }
  int v = c0 + c1 + c2 + c3;
  for (int off = 32; off; off >>= 1) v += __shfl_xor(v, off, 64);
  __shared__ int wsum[4];
  if (lane == 0) wsum[wid] = v;
  __syncthreads();
  if (t == 0) bs[bsoff + lb] = wsum[0] + wsum[1] + wsum[2] + wsum[3];
}

// pass 2: block offset from bs (<=49 sums, one wave), in-block scan, write rp/cursor/inv
__global__ __launch_bounds__(256)
void scan_pass2(int* __restrict__ cC, int* __restrict__ rC, float* __restrict__ vC, int nC,
                int* __restrict__ cW, int* __restrict__ rW, float* __restrict__ vW, int nW,
                int* __restrict__ cR, int* __restrict__ rR, float* __restrict__ vR, int nR,
                const int* __restrict__ bs, int nbC, int nbW, int nbR) {
  const int b = blockIdx.x;
  int* cnt; int* rp; float* inv; int n, lb, bsoff, nb;
  if (b < nbC)            { cnt = cC; rp = rC; inv = vC; n = nC; lb = b;             bsoff = 0;         nb = nbC; }
  else if (b < nbC + nbW) { cnt = cW; rp = rW; inv = vW; n = nW; lb = b - nbC;       bsoff = nbC;       nb = nbW; }
  else                    { cnt = cR; rp = rR; inv = vR; n = nR; lb = b - nbC - nbW; bsoff = nbC + nbW; nb = nbR; }
  const int t = threadIdx.x, lane = t & 63, wid = t >> 6;
  __shared__ int sh_off;
  __shared__ int wsum[4];
  if (wid == 0) {
    int v = (lane < lb) ? bs[bsoff + lane] : 0;
    for (int off = 32; off; off >>= 1) v += __shfl_xor(v, off, 64);
    if (lane == 0) sh_off = v;
  }
  const int base = lb * 1024 + t * 4;
  int c0 = 0, c1 = 0, c2 = 0, c3 = 0;
  if (base + 3 < n) { int4 q = *(const int4*)(cnt + base); c0 = q.x; c1 = q.y; c2 = q.z; c3 = q.w; }
  else {
    if (base < n)     c0 = cnt[base];
    if (base + 1 < n) c1 = cnt[base + 1];
    if (base + 2 < n) c2 = cnt[base + 2];
  }
  const int tsum = c0 + c1 + c2 + c3;
  int isc = tsum;
  for (int off = 1; off < 64; off <<= 1) {
    int y = __shfl_up(isc, off, 64);
    if (lane >= off) isc += y;
  }
  if (lane == 63) wsum[wid] = isc;
  __syncthreads();
  int woff = sh_off;
  for (int w = 0; w < wid; ++w) woff += wsum[w];
  const int e = woff + isc - tsum;
  const int ex0 = e, ex1 = e + c0, ex2 = e + c0 + c1, ex3 = e + c0 + c1 + c2;
  if (base + 3 < n) {
    *(int4*)(rp + base) = make_int4(ex0, ex1, ex2, ex3);
    *(int4*)(cnt + base) = make_int4(ex0, ex1, ex2, ex3);
    *(float4*)(inv + base) = make_float4(1.f / (c0 > 1 ? c0 : 1), 1.f / (c1 > 1 ? c1 : 1),
                                         1.f / (c2 > 1 ? c2 : 1), 1.f / (c3 > 1 ? c3 : 1));
  } else {
    if (base < n)     { rp[base] = ex0;     cnt[base] = ex0;     inv[base] = 1.f / (c0 > 1 ? c0 : 1); }
    if (base + 1 < n) { rp[base + 1] = ex1; cnt[base + 1] = ex1; inv[base + 1] = 1.f / (c1 > 1 ? c1 : 1); }
    if (base + 2 < n) { rp[base + 2] = ex2; cnt[base + 2] = ex2; inv[base + 2] = 1.f / (c2 > 1 ? c2 : 1); }
  }
  if (lb == nb - 1 && t == 255) rp[n] = woff + isc;
}

__global__ void fill_edges(const int* __restrict__ sc, const int* __restrict__ dc,
                           const int* __restrict__ sw, const int* __restrict__ dw,
                           const int* __restrict__ sr, const int* __restrict__ dr,
                           int* curC, int* curW, int* curR,
                           int* eC, int* eW, int* eR, int E_) {
  int i = blockIdx.x * blockDim.x + threadIdx.x;
  const int stride = gridDim.x * blockDim.x;
  for (; i < 3 * E_; i += stride) {
    if (i < E_)          { int p = atomicAdd(&curC[dc[i]], 1); eC[p] = sc[i]; }
    else if (i < 2 * E_) { int j = i - E_;     int p = atomicAdd(&curW[dw[j]], 1); eW[p] = sw[j]; }
    else                 { int j = i - 2 * E_; int p = atomicAdd(&curR[dr[j]], 1); eR[p] = sr[j]; }
  }
}

// ---------------- f32 -> bf16 convert ----------------

__global__ void cvt_bf16(const float4* __restrict__ a, unsigned short* __restrict__ oa, long na4,
                         const float4* __restrict__ b, unsigned short* __restrict__ ob, long nb4) {
  long i = (long)blockIdx.x * blockDim.x + threadIdx.x;
  const long tot = na4 + nb4;
  const long stride = (long)gridDim.x * blockDim.x;
  for (; i < tot; i += stride) {
    const float4* src; unsigned short* dst; long j;
    if (i < na4) { src = a; dst = oa; j = i; } else { src = b; dst = ob; j = i - na4; }
    float4 v = src[j];
    ushort4 o;
    o.x = f2bf(v.x); o.y = f2bf(v.y); o.z = f2bf(v.z); o.w = f2bf(v.w);
    *(ushort4*)(dst + j * 4) = o;
  }
}

// ---------------- weight prep: build W^T [N=256][K] bf16 + combined biases ----------------

__global__ void prep_w(const float* Wl1c, const float* bl1c, const float* Wr1c,
                       const float* Wl1w, const float* bl1w, const float* Wr1w,
                       const float* Wl1r, const float* bl1r, const float* Wr1r,
                       const float* Wl2c, const float* bl2c, const float* Wr2c,
                       const float* Wl2w, const float* bl2w, const float* Wr2w,
                       const float* Wl2r, const float* bl2r, const float* Wr2r,
                       unsigned short* WT, float* bias) {
  const int mat = blockIdx.x >> 8;
  const int nn = blockIdx.x & 255;
  const int t = threadIdx.x;
  if (mat == 0) {  // P1: K=640 = [Wl1c(256); Wl1w(128); Wr1c+Wr1w(256)]
    unsigned short* out = WT + (size_t)nn * 640;
    for (int k = t; k < 640; k += 256) {
      float v;
      if (k < 256)      v = Wl1c[k * 256 + nn];
      else if (k < 384) v = Wl1w[(k - 256) * 256 + nn];
      else              v = Wr1c[(k - 384) * 256 + nn] + Wr1w[(k - 384) * 256 + nn];
      out[k] = f2bf(v);
    }
    if (t == 0) bias[nn] = bl1c[nn] + bl1w[nn];
  } else if (mat == 1) {  // A1: K=384 = [Wl1r(256); Wr1r(128)]
    unsigned short* out = WT + (size_t)256 * 640 + (size_t)nn * 384;
    for (int k = t; k < 384; k += 256) {
      float v = (k < 256) ? Wl1r[k * 256 + nn] : Wr1r[(k - 256) * 256 + nn];
      out[k] = f2bf(v);
    }
    if (t == 0) bias[256 + nn] = bl1r[nn];
  } else if (mat == 2) {  // P2: K=768 = [Wl2c(256); Wl2w(256); Wr2c+Wr2w(256)]
    unsigned short* out = WT + (size_t)256 * (640 + 384) + (size_t)nn * 768;
    for (int k = t; k < 768; k += 256) {
      float v;
      if (k < 256)      v = Wl2c[k * 256 + nn];
      else if (k < 512) v = Wl2w[(k - 256) * 256 + nn];
      else              v = Wr2c[(k - 512) * 256 + nn] + Wr2w[(k - 512) * 256 + nn];
      out[k] = f2bf(v);
    }
    if (t == 0) bias[512 + nn] = bl2c[nn] + bl2w[nn];
  } else {  // A2: K=512 = [Wl2r(256); Wr2r(256)]
    unsigned short* out = WT + (size_t)256 * (640 + 384 + 768) + (size_t)nn * 512;
    for (int k = t; k < 512; k += 256) {
      float v = (k < 256) ? Wl2r[k * 256 + nn] : Wr2r[(k - 256) * 256 + nn];
      out[k] = f2bf(v);
    }
    if (t == 0) bias[768 + nn] = bl2r[nn];
  }
}

// ---------------- aggregation: one wave per dst node, mean of bf16 source rows ----------------

template <int D>
__global__ __launch_bounds__(256)
void agg_mean(const unsigned short* __restrict__ feat, const int* __restrict__ rp,
              const int* __restrict__ es, const float* __restrict__ inv,
              unsigned short* __restrict__ out, int n) {
  const int node = blockIdx.x * 4 + (threadIdx.x >> 6);
  const int lane = threadIdx.x & 63;
  if (node >= n) return;
  const int e0 = rp[node], e1 = rp[node + 1];
  const float sc = inv[node];
  if constexpr (D == 256) {
    const int c0 = lane * 4;
    float a0 = 0, a1 = 0, a2 = 0, a3 = 0;
    int e = e0;
    for (; e + 3 < e1; e += 4) {
      int s0 = es[e], s1 = es[e + 1], s2 = es[e + 2], s3 = es[e + 3];
      ushort4 v0 = *(const ushort4*)(feat + (size_t)s0 * 256 + c0);
      ushort4 v1 = *(const ushort4*)(feat + (size_t)s1 * 256 + c0);
      ushort4 v2 = *(const ushort4*)(feat + (size_t)s2 * 256 + c0);
      ushort4 v3 = *(const ushort4*)(feat + (size_t)s3 * 256 + c0);
      a0 += (bf2f(v0.x) + bf2f(v1.x)) + (bf2f(v2.x) + bf2f(v3.x));
      a1 += (bf2f(v0.y) + bf2f(v1.y)) + (bf2f(v2.y) + bf2f(v3.y));
      a2 += (bf2f(v0.z) + bf2f(v1.z)) + (bf2f(v2.z) + bf2f(v3.z));
      a3 += (bf2f(v0.w) + bf2f(v1.w)) + (bf2f(v2.w) + bf2f(v3.w));
    }
    for (; e < e1; ++e) {
      int s0 = es[e];
      ushort4 v0 = *(const ushort4*)(feat + (size_t)s0 * 256 + c0);
      a0 += bf2f(v0.x); a1 += bf2f(v0.y); a2 += bf2f(v0.z); a3 += bf2f(v0.w);
    }
    ushort4 o;
    o.x = f2bf(a0 * sc); o.y = f2bf(a1 * sc); o.z = f2bf(a2 * sc); o.w = f2bf(a3 * sc);
    *(ushort4*)(out + (size_t)node * 256 + c0) = o;
  } else {
    const int c0 = lane * 2;
    float a0 = 0, a1 = 0;
    int e = e0;
    for (; e + 3 < e1; e += 4) {
      int s0 = es[e], s1 = es[e + 1], s2 = es[e + 2], s3 = es[e + 3];
      ushort2 v0 = *(const ushort2*)(feat + (size_t)s0 * 128 + c0);
      ushort2 v1 = *(const ushort2*)(feat + (size_t)s1 * 128 + c0);
      ushort2 v2 = *(const ushort2*)(feat + (size_t)s2 * 128 + c0);
      ushort2 v3 = *(const ushort2*)(feat + (size_t)s3 * 128 + c0);
      a0 += (bf2f(v0.x) + bf2f(v1.x)) + (bf2f(v2.x) + bf2f(v3.x));
      a1 += (bf2f(v0.y) + bf2f(v1.y)) + (bf2f(v2.y) + bf2f(v3.y));
    }
    for (; e < e1; ++e) {
      int s0 = es[e];
      ushort2 v0 = *(const ushort2*)(feat + (size_t)s0 * 128 + c0);
      a0 += bf2f(v0.x); a1 += bf2f(v0.y);
    }
    ushort2 o; o.x = f2bf(a0 * sc); o.y = f2bf(a1 * sc);
    *(ushort2*)(out + (size_t)node * 128 + c0) = o;
  }
}

// ---------------- segmented-A bf16 MFMA GEMM: C[M x 256] = [segA] @ W^T + bias ----------------

struct Segs {
  const unsigned short *p0, *p1, *p2;
  int ld0, ld1, ld2;
  int ke0, ke1;  // segment end k-offsets (elements); seg2 ends at KTOT
};

template <int KTOT, bool RELU, bool OBF16>
__global__ __launch_bounds__(256, 2)
void gemm_sage(Segs sg, const unsigned short* __restrict__ Wt,
               const float* __restrict__ bias, void* __restrict__ outp, int M) {
  __shared__ alignas(16) unsigned short lsA[128 * 64];
  __shared__ alignas(16) unsigned short lsB[128 * 64];

  const int tid = threadIdx.x;
  const int lane = tid & 63;
  const int wave = tid >> 6;
  const int wr = wave >> 1, wc = wave & 1;
  const int mt = blockIdx.x >> 1, nt = blockIdx.x & 1;

  const floatx4 fzero = {0.f, 0.f, 0.f, 0.f};
  floatx4 acc[4][4];
#pragma unroll
  for (int m = 0; m < 4; ++m)
#pragma unroll
    for (int n = 0; n < 4; ++n) acc[m][n] = fzero;

  const int srow = tid >> 3;        // 0..31: tile row chunk per staging stmt
  const int scol = (tid & 7) * 8;   // element offset within 64-wide k-tile (16B)
  const int arow = wr * 64 + (lane & 15);
  const int brow = wc * 64 + (lane & 15);
  const int kq = (lane >> 4) * 8;

  constexpr int KT = KTOT / 64;
#pragma unroll 1
  for (int kt = 0; kt < KT; ++kt) {
    const int k0 = kt * 64;
    const unsigned short* sp; int sld, skb;
    if (k0 < sg.ke0)      { sp = sg.p0; sld = sg.ld0; skb = 0; }
    else if (k0 < sg.ke1) { sp = sg.p1; sld = sg.ld1; skb = sg.ke0; }
    else                  { sp = sg.p2; sld = sg.ld2; skb = sg.ke1; }

#pragma unroll
    for (int s = 0; s < 4; ++s) {
      int r = s * 32 + srow;
      int g = mt * 128 + r; g = g < M ? g : M - 1;
      gload_lds16(sp + (size_t)g * sld + (k0 - skb) + scol, lsA + r * 64 + scol);
    }
#pragma unroll
    for (int s = 0; s < 4; ++s) {
      int r = s * 32 + srow;
      gload_lds16(Wt + (size_t)(nt * 128 + r) * KTOT + k0 + scol, lsB + r * 64 + scol);
    }
    __syncthreads();  // drain global_load_lds (compiler emits vmcnt(0)) + barrier

    shortx8 af[2][4], bq[2][4];
#pragma unroll
    for (int kk = 0; kk < 2; ++kk)
#pragma unroll
      for (int i = 0; i < 4; ++i) {
        af[kk][i] = *(const shortx8*)(lsA + (arow + i * 16) * 64 + kk * 32 + kq);
        bq[kk][i] = *(const shortx8*)(lsB + (brow + i * 16) * 64 + kk * 32 + kq);
      }
#pragma unroll
    for (int m = 0; m < 4; ++m)
#pragma unroll
      for (int n = 0; n < 4; ++n) {
        acc[m][n] = __builtin_amdgcn_mfma_f32_16x16x32_bf16(af[0][m], bq[0][n], acc[m][n], 0, 0, 0);
        acc[m][n] = __builtin_amdgcn_mfma_f32_16x16x32_bf16(af[1][m], bq[1][n], acc[m][n], 0, 0, 0);
      }
    __syncthreads();  // protect LDS before next stage
  }

  const int lr = (lane >> 4) * 4;
  const int lc = lane & 15;
  const int rb = mt * 128 + wr * 64;
  const int cb = nt * 128 + wc * 64;
#pragma unroll
  for (int m = 0; m < 4; ++m) {
#pragma unroll
    for (int j = 0; j < 4; ++j) {
      const int row = rb + m * 16 + lr + j;
      if (row < M) {
#pragma unroll
        for (int n = 0; n < 4; ++n) {
          const int col = cb + n * 16 + lc;
          float v = acc[m][n][j] + bias[col];
          if (RELU) v = v > 0.f ? v : 0.f;
          if (OBF16) ((unsigned short*)outp)[(size_t)row * 256 + col] = f2bf(v);
          else       ((float*)outp)[(size_t)row * 256 + col] = v;
        }
      }
    }
  }
}

// ---------------- host ----------------

extern "C" void kernel_launch(void* const* d_in, const int* in_sizes, int n_in,
                              void* d_out, int out_size, void* d_ws, size_t ws_size,
                              hipStream_t stream) {
  const float* x_paper = (const float*)d_in[0];
  const float* x_author = (const float*)d_in[1];
  const int* cites_src = (const int*)d_in[2];
  const int* cites_dst = (const int*)d_in[3];
  const int* writes_src = (const int*)d_in[4];
  const int* writes_dst = (const int*)d_in[5];
  const int* rev_src = (const int*)d_in[6];
  const int* rev_dst = (const int*)d_in[7];
  const float* Wl1c = (const float*)d_in[8];  const float* bl1c = (const float*)d_in[9];  const float* Wr1c = (const float*)d_in[10];
  const float* Wl1w = (const float*)d_in[11]; const float* bl1w = (const float*)d_in[12]; const float* Wr1w = (const float*)d_in[13];
  const float* Wl1r = (const float*)d_in[14]; const float* bl1r = (const float*)d_in[15]; const float* Wr1r = (const float*)d_in[16];
  const float* Wl2c = (const float*)d_in[17]; const float* bl2c = (const float*)d_in[18]; const float* Wr2c = (const float*)d_in[19];
  const float* Wl2w = (const float*)d_in[20]; const float* bl2w = (const float*)d_in[21]; const float* Wr2w = (const float*)d_in[22];
  const float* Wl2r = (const float*)d_in[23]; const float* bl2r = (const float*)d_in[24]; const float* Wr2r = (const float*)d_in[25];

  const int NP = in_sizes[0] / 256;  // 50000
  const int NA = in_sizes[1] / 128;  // 25000
  const int E = in_sizes[2];         // 400000

  char* w = (char*)d_ws;
  auto alloc = [&](size_t bytes) -> char* {
    char* p = w;
    w += (bytes + 255) & ~(size_t)255;
    return p;
  };

  unsigned short* xpb = (unsigned short*)alloc((size_t)NP * 256 * 2);
  unsigned short* xab = (unsigned short*)alloc((size_t)NA * 128 * 2);
  unsigned short* mA  = (unsigned short*)alloc((size_t)NP * 256 * 2);
  unsigned short* mB  = (unsigned short*)alloc((size_t)NP * 256 * 2);
  unsigned short* mC  = (unsigned short*)alloc((size_t)NA * 256 * 2);
  unsigned short* p1b = (unsigned short*)alloc((size_t)NP * 256 * 2);
  unsigned short* a1b = (unsigned short*)alloc((size_t)NA * 256 * 2);
  unsigned short* WT  = (unsigned short*)alloc((size_t)2304 * 256 * 2);
  float* bias = (float*)alloc(4 * 256 * 4);
  int* curC = (int*)alloc((size_t)NP * 4);
  int* curW = (int*)alloc((size_t)NP * 4);
  int* curR = (int*)alloc((size_t)NA * 4);
  int* rpC = (int*)alloc((size_t)(NP + 1) * 4);
  int* rpW = (int*)alloc((size_t)(NP + 1) * 4);
  int* rpR = (int*)alloc((size_t)(NA + 1) * 4);
  float* invC = (float*)alloc((size_t)NP * 4);
  float* invW = (float*)alloc((size_t)NP * 4);
  float* invR = (float*)alloc((size_t)NA * 4);
  int* esC = (int*)alloc((size_t)E * 4);
  int* esW = (int*)alloc((size_t)E * 4);
  int* esR = (int*)alloc((size_t)E * 4);
  int* bsums = (int*)alloc(256 * 4);

  // zero edge-count arrays
  hipMemsetAsync(curC, 0, (size_t)NP * 4, stream);
  hipMemsetAsync(curW, 0, (size_t)NP * 4, stream);
  hipMemsetAsync(curR, 0, (size_t)NA * 4, stream);

  // weights (independent) + feature converts
  prep_w<<<1024, 256, 0, stream>>>(Wl1c, bl1c, Wr1c, Wl1w, bl1w, Wr1w, Wl1r, bl1r, Wr1r,
                                   Wl2c, bl2c, Wr2c, Wl2w, bl2w, Wr2w, Wl2r, bl2r, Wr2r,
                                   WT, bias);
  cvt_bf16<<<2048, 256, 0, stream>>>((const float4*)x_paper, xpb, (long)NP * 256 / 4,
                                     (const float4*)x_author, xab, (long)NA * 128 / 4);

  // CSR build (shared by both layers)
  const int nbC = (NP + 1023) / 1024, nbW = (NP + 1023) / 1024, nbR = (NA + 1023) / 1024;
  count_edges<<<2048, 256, 0, stream>>>(cites_dst, writes_dst, rev_dst, curC, curW, curR, E);
  scan_pass1<<<nbC + nbW + nbR, 256, 0, stream>>>(curC, NP, curW, NP, curR, NA, bsums, nbC, nbW);
  scan_pass2<<<nbC + nbW + nbR, 256, 0, stream>>>(curC, rpC, invC, NP, curW, rpW, invW, NP,
                                                  curR, rpR, invR, NA, bsums, nbC, nbW, nbR);
  fill_edges<<<2048, 256, 0, stream>>>(cites_src, cites_dst, writes_src, writes_dst, rev_src, rev_dst,
                                       curC, curW, curR, esC, esW, esR, E);

  // layer-1 aggregation
  agg_mean<256><<<(NP + 3) / 4, 256, 0, stream>>>(xpb, rpC, esC, invC, mA, NP);
  agg_mean<128><<<(NP + 3) / 4, 256, 0, stream>>>(xab, rpW, esW, invW, mB, NP);
  agg_mean<256><<<(NA + 3) / 4, 256, 0, stream>>>(xpb, rpR, esR, invR, mC, NA);

  // layer-1 GEMMs (relu, bf16 out)
  {
    Segs s; s.p0 = mA; s.ld0 = 256; s.ke0 = 256;
    s.p1 = mB; s.ld1 = 128; s.ke1 = 384;
    s.p2 = xpb; s.ld2 = 256;
    gemm_sage<640, true, true><<<((NP + 127) / 128) * 2, 256, 0, stream>>>(s, WT, bias, p1b, NP);
  }
  {
    Segs s; s.p0 = mC; s.ld0 = 256; s.ke0 = 256;
    s.p1 = xab; s.ld1 = 128; s.ke1 = 384;
    s.p2 = xab; s.ld2 = 128;
    gemm_sage<384, true, true><<<((NA + 127) / 128) * 2, 256, 0, stream>>>(
        s, WT + (size_t)256 * 640, bias + 256, a1b, NA);
  }

  // layer-2 aggregation (reuse CSR)
  agg_mean<256><<<(NP + 3) / 4, 256, 0, stream>>>(p1b, rpC, esC, invC, mA, NP);
  agg_mean<256><<<(NP + 3) / 4, 256, 0, stream>>>(a1b, rpW, esW, invW, mB, NP);
  agg_mean<256><<<(NA + 3) / 4, 256, 0, stream>>>(p1b, rpR, esR, invR, mC, NA);

  // layer-2 GEMMs (no relu, f32 out -> d_out)
  {
    Segs s; s.p0 = mA; s.ld0 = 256; s.ke0 = 256;
    s.p1 = mB; s.ld1 = 256; s.ke1 = 512;
    s.p2 = p1b; s.ld2 = 256;
    gemm_sage<768, false, false><<<((NP + 127) / 128) * 2, 256, 0, stream>>>(
        s, WT + (size_t)256 * (640 + 384), bias + 512, d_out, NP);
  }
  {
    Segs s; s.p0 = mC; s.ld0 = 256; s.ke0 = 256;
    s.p1 = a1b; s.ld1 = 256; s.ke1 = 512;
    s.p2 = a1b; s.ld2 = 256;
    gemm_sage<512, false, false><<<((NA + 127) / 128) * 2, 256, 0, stream>>>(
        s, WT + (size_t)256 * (640 + 384 + 768), bias + 768,
        (float*)d_out + (size_t)NP * 256, NA);
  }
}

// Round 4
// 592.204 us; speedup vs baseline: 1.2508x; 1.0189x over previous
//
#include <hip/hip_runtime.h>
#include <cstdint>
#include <cstddef>

#define DEVFN static __device__ __forceinline__

typedef __attribute__((ext_vector_type(8))) short shortx8;   // 8 bf16 (4 VGPRs)
typedef __attribute__((ext_vector_type(4))) float floatx4;   // 4 f32

DEVFN float bf2f(unsigned short u) {
  union { unsigned int i; float f; } v; v.i = ((unsigned int)u) << 16; return v.f;
}
DEVFN unsigned short f2bf(float f) {
  union { float f; unsigned int i; } v; v.f = f;
  unsigned int r = v.i + 0x7FFFu + ((v.i >> 16) & 1u);
  return (unsigned short)(r >> 16);
}

DEVFN void gload_lds16(const void* g, void* l) {
  __builtin_amdgcn_global_load_lds(
      (const __attribute__((address_space(1))) void*)(uintptr_t)g,
      (__attribute__((address_space(3))) void*)(uint32_t)(uintptr_t)l,
      16, 0, 0);
}

// ---------------- CSR build (XCD dst-range partitioned) ----------------
// Group g = blockIdx.x & 7 owns dst range [g*N/8,(g+1)*N/8) per node type.
// All groups scan all edges (reads L3-amortized); counts/scatters stay in the
// owning XCD's L2 -> es lines written to HBM once instead of bouncing.

__global__ __launch_bounds__(256)
void count_edges(const int* __restrict__ dc, const int* __restrict__ dw,
                 const int* __restrict__ dr,
                 int* cntC, int* cntW, int* cntR, int E_, int NP_, int NA_) {
  const int g = blockIdx.x & 7;
  const int loP = (int)((long)g * NP_ / 8), hiP = (int)((long)(g + 1) * NP_ / 8);
  const int loA = (int)((long)g * NA_ / 8), hiA = (int)((long)(g + 1) * NA_ / 8);
  int i = (blockIdx.x >> 3) * blockDim.x + threadIdx.x;
  const int stride = (gridDim.x >> 3) * blockDim.x;
  for (; i < 3 * E_; i += stride) {
    if (i < E_)          { int d = dc[i];          if (d >= loP && d < hiP) atomicAdd(&cntC[d], 1); }
    else if (i < 2 * E_) { int d = dw[i - E_];     if (d >= loP && d < hiP) atomicAdd(&cntW[d], 1); }
    else                 { int d = dr[i - 2 * E_]; if (d >= loA && d < hiA) atomicAdd(&cntR[d], 1); }
  }
}

__global__ __launch_bounds__(256)
void fill_edges(const int* __restrict__ sc, const int* __restrict__ dc,
                const int* __restrict__ sw, const int* __restrict__ dw,
                const int* __restrict__ sr, const int* __restrict__ dr,
                int* curC, int* curW, int* curR,
                int* eC, int* eW, int* eR, int E_, int NP_, int NA_) {
  const int g = blockIdx.x & 7;
  const int loP = (int)((long)g * NP_ / 8), hiP = (int)((long)(g + 1) * NP_ / 8);
  const int loA = (int)((long)g * NA_ / 8), hiA = (int)((long)(g + 1) * NA_ / 8);
  int i = (blockIdx.x >> 3) * blockDim.x + threadIdx.x;
  const int stride = (gridDim.x >> 3) * blockDim.x;
  for (; i < 3 * E_; i += stride) {
    if (i < E_) {
      int d = dc[i];
      if (d >= loP && d < hiP) { int p = atomicAdd(&curC[d], 1); eC[p] = sc[i]; }
    } else if (i < 2 * E_) {
      int j = i - E_; int d = dw[j];
      if (d >= loP && d < hiP) { int p = atomicAdd(&curW[d], 1); eW[p] = sw[j]; }
    } else {
      int j = i - 2 * E_; int d = dr[j];
      if (d >= loA && d < hiA) { int p = atomicAdd(&curR[d], 1); eR[p] = sr[j]; }
    }
  }
}

// hierarchical exclusive scan over three arrays; 1024 elems per block.
__global__ __launch_bounds__(256)
void scan_pass1(const int* __restrict__ cC, int nC,
                const int* __restrict__ cW, int nW,
                const int* __restrict__ cR, int nR,
                int* __restrict__ bs, int nbC, int nbW) {
  const int b = blockIdx.x;
  const int* cnt; int n, lb, bsoff;
  if (b < nbC)            { cnt = cC; n = nC; lb = b;             bsoff = 0; }
  else if (b < nbC + nbW) { cnt = cW; n = nW; lb = b - nbC;       bsoff = nbC; }
  else                    { cnt = cR; n = nR; lb = b - nbC - nbW; bsoff = nbC + nbW; }
  const int t = threadIdx.x, lane = t & 63, wid = t >> 6;
  const int base = lb * 1024 + t * 4;
  int c0 = 0, c1 = 0, c2 = 0, c3 = 0;
  if (base + 3 < n) { int4 q = *(const int4*)(cnt + base); c0 = q.x; c1 = q.y; c2 = q.z; c3 = q.w; }
  else {
    if (base < n)     c0 = cnt[base];
    if (base + 1 < n) c1 = cnt[base + 1];
    if (base + 2 < n) c2 = cnt[base + 2];
  }
  int v = c0 + c1 + c2 + c3;
  for (int off = 32; off; off >>= 1) v += __shfl_xor(v, off, 64);
  __shared__ int wsum[4];
  if (lane == 0) wsum[wid] = v;
  __syncthreads();
  if (t == 0) bs[bsoff + lb] = wsum[0] + wsum[1] + wsum[2] + wsum[3];
}

__global__ __launch_bounds__(256)
void scan_pass2(int* __restrict__ cC, int* __restrict__ rC, float* __restrict__ vC, int nC,
                int* __restrict__ cW, int* __restrict__ rW, float* __restrict__ vW, int nW,
                int* __restrict__ cR, int* __restrict__ rR, float* __restrict__ vR, int nR,
                const int* __restrict__ bs, int nbC, int nbW, int nbR) {
  const int b = blockIdx.x;
  int* cnt; int* rp; float* inv; int n, lb, bsoff, nb;
  if (b < nbC)            { cnt = cC; rp = rC; inv = vC; n = nC; lb = b;             bsoff = 0;         nb = nbC; }
  else if (b < nbC + nbW) { cnt = cW; rp = rW; inv = vW; n = nW; lb = b - nbC;       bsoff = nbC;       nb = nbW; }
  else                    { cnt = cR; rp = rR; inv = vR; n = nR; lb = b - nbC - nbW; bsoff = nbC + nbW; nb = nbR; }
  const int t = threadIdx.x, lane = t & 63, wid = t >> 6;
  __shared__ int sh_off;
  __shared__ int wsum[4];
  if (wid == 0) {
    int v = (lane < lb) ? bs[bsoff + lane] : 0;
    for (int off = 32; off; off >>= 1) v += __shfl_xor(v, off, 64);
    if (lane == 0) sh_off = v;
  }
  const int base = lb * 1024 + t * 4;
  int c0 = 0, c1 = 0, c2 = 0, c3 = 0;
  if (base + 3 < n) { int4 q = *(const int4*)(cnt + base); c0 = q.x; c1 = q.y; c2 = q.z; c3 = q.w; }
  else {
    if (base < n)     c0 = cnt[base];
    if (base + 1 < n) c1 = cnt[base + 1];
    if (base + 2 < n) c2 = cnt[base + 2];
  }
  const int tsum = c0 + c1 + c2 + c3;
  int isc = tsum;
  for (int off = 1; off < 64; off <<= 1) {
    int y = __shfl_up(isc, off, 64);
    if (lane >= off) isc += y;
  }
  if (lane == 63) wsum[wid] = isc;
  __syncthreads();
  int woff = sh_off;
  for (int w = 0; w < wid; ++w) woff += wsum[w];
  const int e = woff + isc - tsum;
  const int ex0 = e, ex1 = e + c0, ex2 = e + c0 + c1, ex3 = e + c0 + c1 + c2;
  if (base + 3 < n) {
    *(int4*)(rp + base) = make_int4(ex0, ex1, ex2, ex3);
    *(int4*)(cnt + base) = make_int4(ex0, ex1, ex2, ex3);
    *(float4*)(inv + base) = make_float4(1.f / (c0 > 1 ? c0 : 1), 1.f / (c1 > 1 ? c1 : 1),
                                         1.f / (c2 > 1 ? c2 : 1), 1.f / (c3 > 1 ? c3 : 1));
  } else {
    if (base < n)     { rp[base] = ex0;     cnt[base] = ex0;     inv[base] = 1.f / (c0 > 1 ? c0 : 1); }
    if (base + 1 < n) { rp[base + 1] = ex1; cnt[base + 1] = ex1; inv[base + 1] = 1.f / (c1 > 1 ? c1 : 1); }
    if (base + 2 < n) { rp[base + 2] = ex2; cnt[base + 2] = ex2; inv[base + 2] = 1.f / (c2 > 1 ? c2 : 1); }
  }
  if (lb == nb - 1 && t == 255) rp[n] = woff + isc;
}

// ---------------- f32 -> bf16 convert ----------------

__global__ void cvt_bf16(const float4* __restrict__ a, unsigned short* __restrict__ oa, long na4,
                         const float4* __restrict__ b, unsigned short* __restrict__ ob, long nb4) {
  long i = (long)blockIdx.x * blockDim.x + threadIdx.x;
  const long tot = na4 + nb4;
  const long stride = (long)gridDim.x * blockDim.x;
  for (; i < tot; i += stride) {
    const float4* src; unsigned short* dst; long j;
    if (i < na4) { src = a; dst = oa; j = i; } else { src = b; dst = ob; j = i - na4; }
    float4 v = src[j];
    ushort4 o;
    o.x = f2bf(v.x); o.y = f2bf(v.y); o.z = f2bf(v.z); o.w = f2bf(v.w);
    *(ushort4*)(dst + j * 4) = o;
  }
}

// ---------------- weight prep: build W^T [N=256][K] bf16 + combined biases ----------------

__global__ void prep_w(const float* Wl1c, const float* bl1c, const float* Wr1c,
                       const float* Wl1w, const float* bl1w, const float* Wr1w,
                       const float* Wl1r, const float* bl1r, const float* Wr1r,
                       const float* Wl2c, const float* bl2c, const float* Wr2c,
                       const float* Wl2w, const float* bl2w, const float* Wr2w,
                       const float* Wl2r, const float* bl2r, const float* Wr2r,
                       unsigned short* WT, float* bias) {
  const int mat = blockIdx.x >> 8;
  const int nn = blockIdx.x & 255;
  const int t = threadIdx.x;
  if (mat == 0) {  // P1: K=640 = [Wl1c(256); Wl1w(128); Wr1c+Wr1w(256)]
    unsigned short* out = WT + (size_t)nn * 640;
    for (int k = t; k < 640; k += 256) {
      float v;
      if (k < 256)      v = Wl1c[k * 256 + nn];
      else if (k < 384) v = Wl1w[(k - 256) * 256 + nn];
      else              v = Wr1c[(k - 384) * 256 + nn] + Wr1w[(k - 384) * 256 + nn];
      out[k] = f2bf(v);
    }
    if (t == 0) bias[nn] = bl1c[nn] + bl1w[nn];
  } else if (mat == 1) {  // A1: K=384 = [Wl1r(256); Wr1r(128)]
    unsigned short* out = WT + (size_t)256 * 640 + (size_t)nn * 384;
    for (int k = t; k < 384; k += 256) {
      float v = (k < 256) ? Wl1r[k * 256 + nn] : Wr1r[(k - 256) * 256 + nn];
      out[k] = f2bf(v);
    }
    if (t == 0) bias[256 + nn] = bl1r[nn];
  } else if (mat == 2) {  // P2: K=768 = [Wl2c(256); Wl2w(256); Wr2c+Wr2w(256)]
    unsigned short* out = WT + (size_t)256 * (640 + 384) + (size_t)nn * 768;
    for (int k = t; k < 768; k += 256) {
      float v;
      if (k < 256)      v = Wl2c[k * 256 + nn];
      else if (k < 512) v = Wl2w[(k - 256) * 256 + nn];
      else              v = Wr2c[(k - 512) * 256 + nn] + Wr2w[(k - 512) * 256 + nn];
      out[k] = f2bf(v);
    }
    if (t == 0) bias[512 + nn] = bl2c[nn] + bl2w[nn];
  } else {  // A2: K=512 = [Wl2r(256); Wr2r(256)]
    unsigned short* out = WT + (size_t)256 * (640 + 384 + 768) + (size_t)nn * 512;
    for (int k = t; k < 512; k += 256) {
      float v = (k < 256) ? Wl2r[k * 256 + nn] : Wr2r[(k - 256) * 256 + nn];
      out[k] = f2bf(v);
    }
    if (t == 0) bias[768 + nn] = bl2r[nn];
  }
}

// ---------------- aggregation: one wave per dst node, mean of bf16 source rows ----------------

template <int D>
__global__ __launch_bounds__(256)
void agg_mean(const unsigned short* __restrict__ feat, const int* __restrict__ rp,
              const int* __restrict__ es, const float* __restrict__ inv,
              unsigned short* __restrict__ out, int n) {
  const int node = blockIdx.x * 4 + (threadIdx.x >> 6);
  const int lane = threadIdx.x & 63;
  if (node >= n) return;
  const int e0 = rp[node], e1 = rp[node + 1];
  const float sc = inv[node];
  if constexpr (D == 256) {
    const int c0 = lane * 4;
    float a0 = 0, a1 = 0, a2 = 0, a3 = 0;
    int e = e0;
    for (; e + 3 < e1; e += 4) {
      int s0 = es[e], s1 = es[e + 1], s2 = es[e + 2], s3 = es[e + 3];
      ushort4 v0 = *(const ushort4*)(feat + (size_t)s0 * 256 + c0);
      ushort4 v1 = *(const ushort4*)(feat + (size_t)s1 * 256 + c0);
      ushort4 v2 = *(const ushort4*)(feat + (size_t)s2 * 256 + c0);
      ushort4 v3 = *(const ushort4*)(feat + (size_t)s3 * 256 + c0);
      a0 += (bf2f(v0.x) + bf2f(v1.x)) + (bf2f(v2.x) + bf2f(v3.x));
      a1 += (bf2f(v0.y) + bf2f(v1.y)) + (bf2f(v2.y) + bf2f(v3.y));
      a2 += (bf2f(v0.z) + bf2f(v1.z)) + (bf2f(v2.z) + bf2f(v3.z));
      a3 += (bf2f(v0.w) + bf2f(v1.w)) + (bf2f(v2.w) + bf2f(v3.w));
    }
    for (; e < e1; ++e) {
      int s0 = es[e];
      ushort4 v0 = *(const ushort4*)(feat + (size_t)s0 * 256 + c0);
      a0 += bf2f(v0.x); a1 += bf2f(v0.y); a2 += bf2f(v0.z); a3 += bf2f(v0.w);
    }
    ushort4 o;
    o.x = f2bf(a0 * sc); o.y = f2bf(a1 * sc); o.z = f2bf(a2 * sc); o.w = f2bf(a3 * sc);
    *(ushort4*)(out + (size_t)node * 256 + c0) = o;
  } else {
    const int c0 = lane * 2;
    float a0 = 0, a1 = 0;
    int e = e0;
    for (; e + 3 < e1; e += 4) {
      int s0 = es[e], s1 = es[e + 1], s2 = es[e + 2], s3 = es[e + 3];
      ushort2 v0 = *(const ushort2*)(feat + (size_t)s0 * 128 + c0);
      ushort2 v1 = *(const ushort2*)(feat + (size_t)s1 * 128 + c0);
      ushort2 v2 = *(const ushort2*)(feat + (size_t)s2 * 128 + c0);
      ushort2 v3 = *(const ushort2*)(feat + (size_t)s3 * 128 + c0);
      a0 += (bf2f(v0.x) + bf2f(v1.x)) + (bf2f(v2.x) + bf2f(v3.x));
      a1 += (bf2f(v0.y) + bf2f(v1.y)) + (bf2f(v2.y) + bf2f(v3.y));
    }
    for (; e < e1; ++e) {
      int s0 = es[e];
      ushort2 v0 = *(const ushort2*)(feat + (size_t)s0 * 128 + c0);
      a0 += bf2f(v0.x); a1 += bf2f(v0.y);
    }
    ushort2 o; o.x = f2bf(a0 * sc); o.y = f2bf(a1 * sc);
    *(ushort2*)(out + (size_t)node * 128 + c0) = o;
  }
}

// ---------------- segmented-A bf16 MFMA GEMM: C[M x 256] = [segA] @ W^T + bias ----------------

struct Segs {
  const unsigned short *p0, *p1, *p2;
  int ld0, ld1, ld2;
  int ke0, ke1;  // segment end k-offsets (elements); seg2 ends at KTOT
};

template <int KTOT, bool RELU, bool OBF16>
__global__ __launch_bounds__(256, 2)
void gemm_sage(Segs sg, const unsigned short* __restrict__ Wt,
               const float* __restrict__ bias, void* __restrict__ outp, int M) {
  __shared__ alignas(16) unsigned short lsA[128 * 64];
  __shared__ alignas(16) unsigned short lsB[128 * 64];

  const int tid = threadIdx.x;
  const int lane = tid & 63;
  const int wave = tid >> 6;
  const int wr = wave >> 1, wc = wave & 1;
  const int mt = blockIdx.x >> 1, nt = blockIdx.x & 1;

  const floatx4 fzero = {0.f, 0.f, 0.f, 0.f};
  floatx4 acc[4][4];
#pragma unroll
  for (int m = 0; m < 4; ++m)
#pragma unroll
    for (int n = 0; n < 4; ++n) acc[m][n] = fzero;

  const int srow = tid >> 3;        // 0..31: tile row chunk per staging stmt
  const int scol = (tid & 7) * 8;   // element offset within 64-wide k-tile (16B)
  const int arow = wr * 64 + (lane & 15);
  const int brow = wc * 64 + (lane & 15);
  const int kq = (lane >> 4) * 8;

  constexpr int KT = KTOT / 64;
#pragma unroll 1
  for (int kt = 0; kt < KT; ++kt) {
    const int k0 = kt * 64;
    const unsigned short* sp; int sld, skb;
    if (k0 < sg.ke0)      { sp = sg.p0; sld = sg.ld0; skb = 0; }
    else if (k0 < sg.ke1) { sp = sg.p1; sld = sg.ld1; skb = sg.ke0; }
    else                  { sp = sg.p2; sld = sg.ld2; skb = sg.ke1; }

#pragma unroll
    for (int s = 0; s < 4; ++s) {
      int r = s * 32 + srow;
      int g = mt * 128 + r; g = g < M ? g : M - 1;
      gload_lds16(sp + (size_t)g * sld + (k0 - skb) + scol, lsA + r * 64 + scol);
    }
#pragma unroll
    for (int s = 0; s < 4; ++s) {
      int r = s * 32 + srow;
      gload_lds16(Wt + (size_t)(nt * 128 + r) * KTOT + k0 + scol, lsB + r * 64 + scol);
    }
    __syncthreads();  // drain global_load_lds (compiler emits vmcnt(0)) + barrier

    shortx8 af[2][4], bq[2][4];
#pragma unroll
    for (int kk = 0; kk < 2; ++kk)
#pragma unroll
      for (int i = 0; i < 4; ++i) {
        af[kk][i] = *(const shortx8*)(lsA + (arow + i * 16) * 64 + kk * 32 + kq);
        bq[kk][i] = *(const shortx8*)(lsB + (brow + i * 16) * 64 + kk * 32 + kq);
      }
#pragma unroll
    for (int m = 0; m < 4; ++m)
#pragma unroll
      for (int n = 0; n < 4; ++n) {
        acc[m][n] = __builtin_amdgcn_mfma_f32_16x16x32_bf16(af[0][m], bq[0][n], acc[m][n], 0, 0, 0);
        acc[m][n] = __builtin_amdgcn_mfma_f32_16x16x32_bf16(af[1][m], bq[1][n], acc[m][n], 0, 0, 0);
      }
    __syncthreads();  // protect LDS before next stage
  }

  const int lr = (lane >> 4) * 4;
  const int lc = lane & 15;
  const int rb = mt * 128 + wr * 64;
  const int cb = nt * 128 + wc * 64;
#pragma unroll
  for (int m = 0; m < 4; ++m) {
#pragma unroll
    for (int j = 0; j < 4; ++j) {
      const int row = rb + m * 16 + lr + j;
      if (row < M) {
#pragma unroll
        for (int n = 0; n < 4; ++n) {
          const int col = cb + n * 16 + lc;
          float v = acc[m][n][j] + bias[col];
          if (RELU) v = v > 0.f ? v : 0.f;
          if (OBF16) ((unsigned short*)outp)[(size_t)row * 256 + col] = f2bf(v);
          else       ((float*)outp)[(size_t)row * 256 + col] = v;
        }
      }
    }
  }
}

// ---------------- host ----------------

extern "C" void kernel_launch(void* const* d_in, const int* in_sizes, int n_in,
                              void* d_out, int out_size, void* d_ws, size_t ws_size,
                              hipStream_t stream) {
  const float* x_paper = (const float*)d_in[0];
  const float* x_author = (const float*)d_in[1];
  const int* cites_src = (const int*)d_in[2];
  const int* cites_dst = (const int*)d_in[3];
  const int* writes_src = (const int*)d_in[4];
  const int* writes_dst = (const int*)d_in[5];
  const int* rev_src = (const int*)d_in[6];
  const int* rev_dst = (const int*)d_in[7];
  const float* Wl1c = (const float*)d_in[8];  const float* bl1c = (const float*)d_in[9];  const float* Wr1c = (const float*)d_in[10];
  const float* Wl1w = (const float*)d_in[11]; const float* bl1w = (const float*)d_in[12]; const float* Wr1w = (const float*)d_in[13];
  const float* Wl1r = (const float*)d_in[14]; const float* bl1r = (const float*)d_in[15]; const float* Wr1r = (const float*)d_in[16];
  const float* Wl2c = (const float*)d_in[17]; const float* bl2c = (const float*)d_in[18]; const float* Wr2c = (const float*)d_in[19];
  const float* Wl2w = (const float*)d_in[20]; const float* bl2w = (const float*)d_in[21]; const float* Wr2w = (const float*)d_in[22];
  const float* Wl2r = (const float*)d_in[23]; const float* bl2r = (const float*)d_in[24]; const float* Wr2r = (const float*)d_in[25];

  const int NP = in_sizes[0] / 256;  // 50000
  const int NA = in_sizes[1] / 128;  // 25000
  const int E = in_sizes[2];         // 400000

  char* w = (char*)d_ws;
  auto alloc = [&](size_t bytes) -> char* {
    char* p = w;
    w += (bytes + 255) & ~(size_t)255;
    return p;
  };

  unsigned short* xpb = (unsigned short*)alloc((size_t)NP * 256 * 2);
  unsigned short* xab = (unsigned short*)alloc((size_t)NA * 128 * 2);
  unsigned short* mA  = (unsigned short*)alloc((size_t)NP * 256 * 2);
  unsigned short* mB  = (unsigned short*)alloc((size_t)NP * 256 * 2);
  unsigned short* mC  = (unsigned short*)alloc((size_t)NA * 256 * 2);
  unsigned short* p1b = (unsigned short*)alloc((size_t)NP * 256 * 2);
  unsigned short* a1b = (unsigned short*)alloc((size_t)NA * 256 * 2);
  unsigned short* WT  = (unsigned short*)alloc((size_t)2304 * 256 * 2);
  float* bias = (float*)alloc(4 * 256 * 4);
  int* curC = (int*)alloc((size_t)NP * 4);
  int* curW = (int*)alloc((size_t)NP * 4);
  int* curR = (int*)alloc((size_t)NA * 4);
  int* rpC = (int*)alloc((size_t)(NP + 1) * 4);
  int* rpW = (int*)alloc((size_t)(NP + 1) * 4);
  int* rpR = (int*)alloc((size_t)(NA + 1) * 4);
  float* invC = (float*)alloc((size_t)NP * 4);
  float* invW = (float*)alloc((size_t)NP * 4);
  float* invR = (float*)alloc((size_t)NA * 4);
  int* esC = (int*)alloc((size_t)E * 4);
  int* esW = (int*)alloc((size_t)E * 4);
  int* esR = (int*)alloc((size_t)E * 4);
  int* bsums = (int*)alloc(256 * 4);

  // zero edge-count arrays
  hipMemsetAsync(curC, 0, (size_t)NP * 4, stream);
  hipMemsetAsync(curW, 0, (size_t)NP * 4, stream);
  hipMemsetAsync(curR, 0, (size_t)NA * 4, stream);

  // weights (independent) + feature converts
  prep_w<<<1024, 256, 0, stream>>>(Wl1c, bl1c, Wr1c, Wl1w, bl1w, Wr1w, Wl1r, bl1r, Wr1r,
                                   Wl2c, bl2c, Wr2c, Wl2w, bl2w, Wr2w, Wl2r, bl2r, Wr2r,
                                   WT, bias);
  cvt_bf16<<<2048, 256, 0, stream>>>((const float4*)x_paper, xpb, (long)NP * 256 / 4,
                                     (const float4*)x_author, xab, (long)NA * 128 / 4);

  // CSR build (shared by both layers)
  const int nbC = (NP + 1023) / 1024, nbW = (NP + 1023) / 1024, nbR = (NA + 1023) / 1024;
  count_edges<<<2048, 256, 0, stream>>>(cites_dst, writes_dst, rev_dst, curC, curW, curR, E, NP, NA);
  scan_pass1<<<nbC + nbW + nbR, 256, 0, stream>>>(curC, NP, curW, NP, curR, NA, bsums, nbC, nbW);
  scan_pass2<<<nbC + nbW + nbR, 256, 0, stream>>>(curC, rpC, invC, NP, curW, rpW, invW, NP,
                                                  curR, rpR, invR, NA, bsums, nbC, nbW, nbR);
  fill_edges<<<2048, 256, 0, stream>>>(cites_src, cites_dst, writes_src, writes_dst, rev_src, rev_dst,
                                       curC, curW, curR, esC, esW, esR, E, NP, NA);

  // layer-1 aggregation
  agg_mean<256><<<(NP + 3) / 4, 256, 0, stream>>>(xpb, rpC, esC, invC, mA, NP);
  agg_mean<128><<<(NP + 3) / 4, 256, 0, stream>>>(xab, rpW, esW, invW, mB, NP);
  agg_mean<256><<<(NA + 3) / 4, 256, 0, stream>>>(xpb, rpR, esR, invR, mC, NA);

  // layer-1 GEMMs (relu, bf16 out)
  {
    Segs s; s.p0 = mA; s.ld0 = 256; s.ke0 = 256;
    s.p1 = mB; s.ld1 = 128; s.ke1 = 384;
    s.p2 = xpb; s.ld2 = 256;
    gemm_sage<640, true, true><<<((NP + 127) / 128) * 2, 256, 0, stream>>>(s, WT, bias, p1b, NP);
  }
  {
    Segs s; s.p0 = mC; s.ld0 = 256; s.ke0 = 256;
    s.p1 = xab; s.ld1 = 128; s.ke1 = 384;
    s.p2 = xab; s.ld2 = 128;
    gemm_sage<384, true, true><<<((NA + 127) / 128) * 2, 256, 0, stream>>>(
        s, WT + (size_t)256 * 640, bias + 256, a1b, NA);
  }

  // layer-2 aggregation (reuse CSR)
  agg_mean<256><<<(NP + 3) / 4, 256, 0, stream>>>(p1b, rpC, esC, invC, mA, NP);
  agg_mean<256><<<(NP + 3) / 4, 256, 0, stream>>>(a1b, rpW, esW, invW, mB, NP);
  agg_mean<256><<<(NA + 3) / 4, 256, 0, stream>>>(p1b, rpR, esR, invR, mC, NA);

  // layer-2 GEMMs (no relu, f32 out -> d_out)
  {
    Segs s; s.p0 = mA; s.ld0 = 256; s.ke0 = 256;
    s.p1 = mB; s.ld1 = 256; s.ke1 = 512;
    s.p2 = p1b; s.ld2 = 256;
    gemm_sage<768, false, false><<<((NP + 127) / 128) * 2, 256, 0, stream>>>(
        s, WT + (size_t)256 * (640 + 384), bias + 512, d_out, NP);
  }
  {
    Segs s; s.p0 = mC; s.ld0 = 256; s.ke0 = 256;
    s.p1 = a1b; s.ld1 = 256; s.ke1 = 512;
    s.p2 = a1b; s.ld2 = 256;
    gemm_sage<512, false, false><<<((NA + 127) / 128) * 2, 256, 0, stream>>>(
        s, WT + (size_t)256 * (640 + 384 + 768), bias + 768,
        (float*)d_out + (size_t)NP * 256, NA);
  }
}